// Round 5
// baseline (99.443 us; speedup 1.0000x reference)
//
#include <hip/hip_runtime.h>

// DendralNeuron: out[b,d] = min( min_f(x[b,f]-Wmin[d,f]), min_f(Wmax[d,f]-x[b,f]) )
// Tropical "min-GEMM". R8 changes vs R7 (49.7us min-kernel, occupancy 18%,
// LDS pipe ~47% busy, VALU ~60%, stalls dominate):
//  (a) x REMOVED from LDS: threads sharing ty read identical x addresses ->
//      direct global loads are HW-merged broadcasts (L1-hit, x slice is
//      2KB/chunk/block). Shifts x traffic LDS->VMEM pipe; LDS reads per
//      f-step 12 -> 8 (W only), LDS-pipe floor 23.5 -> 15.7us.
//  (b) LDS/block 30.7KB -> 12.3KB (W double-buffer only); live VGPRs ~90
//      -> 5 waves/SIMD instead of 4.
//  (c) BK 16->8, ZSPLIT 7->14: grid 16x8x14 = 1792 blocks = exactly 7/CU,
//      no tail imbalance, resident-block queue stays full.
//  (d) keep __launch_bounds__(256,2): R4 proved (256,4) squeezes to 64 VGPR
//      and spills; (256,2) measured honest 120 VGPR, no spills.
// Inner math unchanged: 4 v_pk_add_f32 (packed subs) + 4 v_min3 per
// (r,c)-per-4-features = 2 VALU insts per (b,d,f) triple = ISA floor.

constexpr int F_DIM = 784;
constexpr int BM = 64;
constexpr int BN = 64;
constexpr int BK = 8;
constexpr int LSTR = BK + 4;          // 12 floats: rows 48B apart, 16B-aligned,
                                      // tx*12 mod 32 banks -> 2-way max (free)
constexpr int NCHUNK = F_DIM / BK;    // 98
constexpr int ZSPLIT = 14;            // F-split: 7 chunks of 8 per z-slice
constexpr int CPZ = NCHUNK / ZSPLIT;  // 7

typedef float f4v __attribute__((ext_vector_type(4)));
typedef float f2v __attribute__((ext_vector_type(2)));

__global__ __launch_bounds__(256, 4)
void dendral_init_kernel(float* __restrict__ out) {
  const int i = blockIdx.x * 256 + threadIdx.x;
  const float inf = __builtin_inff();
  f4v v = {inf, inf, inf, inf};
  ((f4v*)out)[i] = v;
}

__device__ inline void atomic_min_float(float* addr, float v) {
  if (v >= 0.0f) atomicMin((int*)addr, __float_as_int(v));
  else           atomicMax((unsigned int*)addr, __float_as_uint(v));
}

__global__ __launch_bounds__(256, 2)
void dendral_min_kernel(const float* __restrict__ x,
                        const float* __restrict__ wmin,
                        const float* __restrict__ wmax,
                        float* __restrict__ out, int D) {
  __shared__ float lwn[2][BN * LSTR];   // wmin tile [64][12] x2 buf
  __shared__ float lwx[2][BN * LSTR];   // wmax tile [64][12] x2 buf

  const int t  = threadIdx.x;
  const int tx = t & 15;              // d-group: cols tx + 16c, c=0..3
  const int ty = t >> 4;              // b-group: rows ty + 16r, r=0..3
  const int b0 = blockIdx.x * BM;
  const int d0 = blockIdx.y * BN;
  const int c0 = blockIdx.z * CPZ;
  const int c1 = c0 + CPZ;

  // W staging: wmin+wmax tiles 2 x 64x8 = 256 float4 (1/thread, wave split).
  const int wt = t >> 7;              // 0 -> wmin (waves 0,1), 1 -> wmax (2,3)
  const int wr = (t & 127) >> 1;      // 0..63
  const int wc = (t & 1) << 2;        // 0 or 4

  const float* wg = (wt ? wmax : wmin) + (size_t)(d0 + wr) * F_DIM + wc;
  float* lds_w = (wt ? &lwx[0][0] : &lwn[0][0]) + wr * LSTR + wc;
  constexpr int BUFSTRIDE_W = BN * LSTR;

  // x row base pointers (broadcast loads: 16 lanes share each address).
  const float* xp0 = x + (size_t)(b0 + ty)      * F_DIM;
  const float* xp1 = x + (size_t)(b0 + ty + 16) * F_DIM;
  const float* xp2 = x + (size_t)(b0 + ty + 32) * F_DIM;
  const float* xp3 = x + (size_t)(b0 + ty + 48) * F_DIM;

  // Prefetch + stage first chunk's W into buffer 0.
  f4v pw = *(const f4v*)(wg + c0 * BK);
  *(f4v*)lds_w = pw;
  __syncthreads();

  float acc[4][4];
#pragma unroll
  for (int r = 0; r < 4; ++r)
#pragma unroll
    for (int c = 0; c < 4; ++c)
      acc[r][c] = __builtin_inff();

  int cur = 0;
  for (int kc = c0; kc < c1; ++kc) {
    const bool more = (kc + 1 < c1);
    if (more)                          // register prefetch of next chunk's W
      pw = *(const f4v*)(wg + (kc + 1) * BK);

    const float* lnb = &lwn[cur][tx * LSTR];
    const float* lwb = &lwx[cur][tx * LSTR];
#pragma unroll
    for (int f = 0; f < BK; f += 4) {
      // x fragments: direct global (L1 broadcast), no LDS round-trip.
      f4v xv[4];
      xv[0] = *(const f4v*)(xp0 + kc * BK + f);
      xv[1] = *(const f4v*)(xp1 + kc * BK + f);
      xv[2] = *(const f4v*)(xp2 + kc * BK + f);
      xv[3] = *(const f4v*)(xp3 + kc * BK + f);
      f4v nv[4], wv[4];
#pragma unroll
      for (int c = 0; c < 4; ++c) {
        nv[c] = *(const f4v*)&lnb[c * 16 * LSTR + f];
        wv[c] = *(const f4v*)&lwb[c * 16 * LSTR + f];
      }
#pragma unroll
      for (int r = 0; r < 4; ++r)
#pragma unroll
        for (int c = 0; c < 4; ++c) {
          // d1 = x - wmin (L1 path), d2 = wmax - x (L2 path); packed subs.
          f2v d1lo = xv[r].xy - nv[c].xy;
          f2v d1hi = xv[r].zw - nv[c].zw;
          f2v d2lo = wv[c].xy - xv[r].xy;
          f2v d2hi = wv[c].zw - xv[r].zw;
          // 8-value min folded into acc via 4 v_min3.
          float t1 = fminf(fminf(d1lo.x, d1lo.y), d1hi.x);
          float t2 = fminf(fminf(d1hi.y, d2lo.x), d2lo.y);
          float t3 = fminf(fminf(d2hi.x, d2hi.y), acc[r][c]);
          acc[r][c] = fminf(fminf(t1, t2), t3);
        }
    }

    if (more) {                       // stage next chunk's W into other buffer
      const int nxt = cur ^ 1;
      *(f4v*)(lds_w + nxt * BUFSTRIDE_W) = pw;
      cur = nxt;
    }
    __syncthreads();                  // single barrier per chunk
  }

  // Combine this z-slice's partial into out via device-scope atomic min.
#pragma unroll
  for (int r = 0; r < 4; ++r)
#pragma unroll
    for (int c = 0; c < 4; ++c) {
      const int b = b0 + ty + 16 * r;
      const int d = d0 + tx + 16 * c;
      atomic_min_float(&out[(size_t)b * D + d], acc[r][c]);
    }
}

extern "C" void kernel_launch(void* const* d_in, const int* in_sizes, int n_in,
                              void* d_out, int out_size, void* d_ws, size_t ws_size,
                              hipStream_t stream) {
  const float* x    = (const float*)d_in[0];
  const float* wmin = (const float*)d_in[1];
  const float* wmax = (const float*)d_in[2];
  float* out = (float*)d_out;
  const int B = in_sizes[0] / F_DIM;    // 1024 (element-count convention)
  const int D = in_sizes[1] / F_DIM;    // 512

  // Full-coverage init: B*D floats / (4 per thread * 256 threads) blocks.
  dendral_init_kernel<<<(B * D) / 1024, 256, 0, stream>>>(out);

  dim3 grid(B / BM, D / BN, ZSPLIT);    // 16 x 8 x 14 = 1792 blocks = 7/CU
  dendral_min_kernel<<<grid, 256, 0, stream>>>(x, wmin, wmax, out, D);
  (void)n_in; (void)d_ws; (void)ws_size; (void)out_size;
}